// Round 6
// baseline (532.336 us; speedup 1.0000x reference)
//
#include <hip/hip_runtime.h>

#define NN 262144
#define DD 32
#define HH 31
#define KK 21
#define CAP 16384                 // per-bucket capacity; rows/bucket ~12483
#define ENTRIES (KK * CAP)

// ---------------- Kernel 0: pad/transpose weights + zero cursors ------------
// W1Tp[k][e][d] (32x32, zero-padded), b1p[k][32], w2p[k][32] (zero-padded).
__global__ __launch_bounds__(256) void prep_kernel(
    const float* __restrict__ W1,   // [K][d][e]
    const float* __restrict__ b1,   // [K][HH]
    const float* __restrict__ W2,   // [K][HH]
    float* __restrict__ W1Tp,       // [K][32][32]
    float* __restrict__ b1p,        // [K][32]
    float* __restrict__ w2p,        // [K][32]
    int* __restrict__ cursors)
{
    const int idx = blockIdx.x * 256 + threadIdx.x;
    if (blockIdx.x == 0 && threadIdx.x < KK) cursors[threadIdx.x] = 0;
    if (idx < KK * 1024) {
        const int k = idx >> 10, r = idx & 1023, e = r >> 5, d = r & 31;
        W1Tp[idx] = (e < HH && d < HH) ? W1[k * HH * HH + d * HH + e] : 0.0f;
    } else if (idx < KK * 1024 + KK * 32) {
        const int j = idx - KK * 1024, k = j >> 5, e = j & 31;
        b1p[j] = (e < HH) ? b1[k * HH + e] : 0.0f;
    } else if (idx < KK * 1024 + 2 * KK * 32) {
        const int j = idx - KK * 1024 - KK * 32, k = j >> 5, e = j & 31;
        w2p[j] = (e < HH) ? W2[k * HH + e] : 0.0f;
    }
}

// ---------------- Kernel 1: bucketize rows by t ----------------
__global__ __launch_bounds__(256) void bucketize_kernel(
    const float* __restrict__ x,
    int* __restrict__ entries,    // [KK][CAP]
    int* __restrict__ cursors,    // [KK], zeroed by prep_kernel
    float* __restrict__ out)
{
    __shared__ int lcnt[KK];
    __shared__ int lbase[KK];
    __shared__ int lrank[KK];

    const int tid = threadIdx.x;
    if (tid < KK) { lcnt[tid] = 0; lrank[tid] = 0; }
    __syncthreads();

    const int n = blockIdx.x * 256 + tid;
    const float t = x[n * DD];

    const float edges[KK + 1] = {
        0.0f, 0.1f, 0.2f, 0.3f, 0.4f, 0.5f, 0.6f, 0.7f, 0.8f, 0.9f, 1.0f,
        1.1f, 1.2f, 1.3f, 1.4f, 1.5f, 1.6f, 1.7f, 1.8f, 1.9f, 2.0f, 1000.0f
    };
    int k = -1;
    #pragma unroll
    for (int j = 0; j < KK; ++j)
        if (t > edges[j] && t <= edges[j + 1]) k = j;

    if (k >= 0) atomicAdd(&lcnt[k], 1);
    __syncthreads();
    if (tid < KK) lbase[tid] = atomicAdd(&cursors[tid], lcnt[tid]);
    __syncthreads();
    if (k >= 0) {
        const int r = atomicAdd(&lrank[k], 1);
        const int pos = lbase[k] + r;
        if (pos < CAP) entries[k * CAP + pos] = n;
    } else {
        out[n] = 0.0f;
    }
}

// ---------------- Kernel 2: per-bucket MLP, LDS-broadcast weights ----------
// 32 blocks per bucket, 512 rows per block (R=2 rows/thread) -> grid 672.
// k block-uniform -> every ds_read is a same-address broadcast (no conflicts).
// R=2 halves DS ops per row so the per-CU DS pipe stays under the VALU cost.
__global__ __launch_bounds__(256, 2) void mlp_kernel(
    const float* __restrict__ x,
    const float* __restrict__ a,
    const float* __restrict__ b,
    const float* __restrict__ W1Tp,
    const float* __restrict__ b1p,
    const float* __restrict__ w2p,
    const float* __restrict__ b2,
    const int* __restrict__ entries,
    const int* __restrict__ cursors,
    float* __restrict__ out)
{
    __shared__ float sW[32 * 32];
    __shared__ float sb1[32];
    __shared__ float sw2[32];

    const int tid = threadIdx.x;
    const int k = __builtin_amdgcn_readfirstlane((int)blockIdx.x >> 5);
    const int base = ((int)blockIdx.x & 31) * 512;

    int cnt = cursors[k];
    if (cnt > CAP) cnt = CAP;
    if (base >= cnt) return;

    // Stage weights: 4 KB coalesced, once per block.
    reinterpret_cast<float4*>(sW)[tid] =
        reinterpret_cast<const float4*>(W1Tp + k * 1024)[tid];
    if (tid < 8)
        reinterpret_cast<float4*>(sb1)[tid] =
            reinterpret_cast<const float4*>(b1p + k * 32)[tid];
    else if (tid < 16)
        reinterpret_cast<float4*>(sw2)[tid - 8] =
            reinterpret_cast<const float4*>(w2p + k * 32)[tid - 8];
    __syncthreads();

    const int i0 = base + tid;
    const int i1 = base + 256 + tid;
    const bool v0 = i0 < cnt;
    const bool v1 = i1 < cnt;
    const int n0 = v0 ? entries[k * CAP + i0] : 0;
    const int n1 = v1 ? entries[k * CAP + i1] : 0;

    // Gather both rows (16 independent 16B loads), fold into feats.
    float r0[DD], r1[DD];
    {
        const float4* p0 = reinterpret_cast<const float4*>(x) + n0 * (DD / 4);
        const float4* p1 = reinterpret_cast<const float4*>(x) + n1 * (DD / 4);
        #pragma unroll
        for (int i4 = 0; i4 < DD / 4; ++i4) {
            float4 v = p0[i4];
            r0[4 * i4] = v.x; r0[4 * i4 + 1] = v.y; r0[4 * i4 + 2] = v.z; r0[4 * i4 + 3] = v.w;
        }
        #pragma unroll
        for (int i4 = 0; i4 < DD / 4; ++i4) {
            float4 v = p1[i4];
            r1[4 * i4] = v.x; r1[4 * i4 + 1] = v.y; r1[4 * i4 + 2] = v.z; r1[4 * i4 + 3] = v.w;
        }
    }
    float f0[32], f1[32];
    #pragma unroll
    for (int j = 0; j < HH; ++j) {
        const float aj = a[j], bj = b[j];
        f0[j] = fmaf(r0[j + 1], aj, bj);
        f1[j] = fmaf(r1[j + 1], aj, bj);
    }
    f0[31] = 0.0f;
    f1[31] = 0.0f;

    const float bias2 = b2[k];
    float acc0 = bias2, acc1 = bias2;

    #pragma unroll
    for (int eq = 0; eq < 8; ++eq) {
        const float4 hb = reinterpret_cast<const float4*>(sb1)[eq];
        float h00 = hb.x, h01 = hb.y, h02 = hb.z, h03 = hb.w;
        float h10 = hb.x, h11 = hb.y, h12 = hb.z, h13 = hb.w;
        #pragma unroll
        for (int dq = 0; dq < 8; ++dq) {
            const float4 wa = reinterpret_cast<const float4*>(sW + (4 * eq + 0) * 32)[dq];
            const float4 wb = reinterpret_cast<const float4*>(sW + (4 * eq + 1) * 32)[dq];
            const float4 wc = reinterpret_cast<const float4*>(sW + (4 * eq + 2) * 32)[dq];
            const float4 wd = reinterpret_cast<const float4*>(sW + (4 * eq + 3) * 32)[dq];
            const float a0 = f0[4 * dq], a1 = f0[4 * dq + 1], a2 = f0[4 * dq + 2], a3 = f0[4 * dq + 3];
            const float c0 = f1[4 * dq], c1 = f1[4 * dq + 1], c2 = f1[4 * dq + 2], c3 = f1[4 * dq + 3];
            h00 = fmaf(a0, wa.x, h00); h00 = fmaf(a1, wa.y, h00); h00 = fmaf(a2, wa.z, h00); h00 = fmaf(a3, wa.w, h00);
            h01 = fmaf(a0, wb.x, h01); h01 = fmaf(a1, wb.y, h01); h01 = fmaf(a2, wb.z, h01); h01 = fmaf(a3, wb.w, h01);
            h02 = fmaf(a0, wc.x, h02); h02 = fmaf(a1, wc.y, h02); h02 = fmaf(a2, wc.z, h02); h02 = fmaf(a3, wc.w, h02);
            h03 = fmaf(a0, wd.x, h03); h03 = fmaf(a1, wd.y, h03); h03 = fmaf(a2, wd.z, h03); h03 = fmaf(a3, wd.w, h03);
            h10 = fmaf(c0, wa.x, h10); h10 = fmaf(c1, wa.y, h10); h10 = fmaf(c2, wa.z, h10); h10 = fmaf(c3, wa.w, h10);
            h11 = fmaf(c0, wb.x, h11); h11 = fmaf(c1, wb.y, h11); h11 = fmaf(c2, wb.z, h11); h11 = fmaf(c3, wb.w, h11);
            h12 = fmaf(c0, wc.x, h12); h12 = fmaf(c1, wc.y, h12); h12 = fmaf(c2, wc.z, h12); h12 = fmaf(c3, wc.w, h12);
            h13 = fmaf(c0, wd.x, h13); h13 = fmaf(c1, wd.y, h13); h13 = fmaf(c2, wd.z, h13); h13 = fmaf(c3, wd.w, h13);
        }
        const float4 wq = reinterpret_cast<const float4*>(sw2)[eq];
        const float q00 = (h00 >= 0.0f) ? h00 : 0.1f * h00;
        const float q01 = (h01 >= 0.0f) ? h01 : 0.1f * h01;
        const float q02 = (h02 >= 0.0f) ? h02 : 0.1f * h02;
        const float q03 = (h03 >= 0.0f) ? h03 : 0.1f * h03;
        const float q10 = (h10 >= 0.0f) ? h10 : 0.1f * h10;
        const float q11 = (h11 >= 0.0f) ? h11 : 0.1f * h11;
        const float q12 = (h12 >= 0.0f) ? h12 : 0.1f * h12;
        const float q13 = (h13 >= 0.0f) ? h13 : 0.1f * h13;
        acc0 = fmaf(q00, wq.x, acc0); acc0 = fmaf(q01, wq.y, acc0);
        acc0 = fmaf(q02, wq.z, acc0); acc0 = fmaf(q03, wq.w, acc0);
        acc1 = fmaf(q10, wq.x, acc1); acc1 = fmaf(q11, wq.y, acc1);
        acc1 = fmaf(q12, wq.z, acc1); acc1 = fmaf(q13, wq.w, acc1);
    }

    if (v0) out[n0] = acc0;
    if (v1) out[n1] = acc1;
}

extern "C" void kernel_launch(void* const* d_in, const int* in_sizes, int n_in,
                              void* d_out, int out_size, void* d_ws, size_t ws_size,
                              hipStream_t stream) {
    const float* x  = (const float*)d_in[0];
    const float* a  = (const float*)d_in[1];
    const float* b  = (const float*)d_in[2];
    const float* W1 = (const float*)d_in[3];
    const float* b1 = (const float*)d_in[4];
    const float* W2 = (const float*)d_in[5];
    const float* b2 = (const float*)d_in[6];
    float* out = (float*)d_out;

    int* entries = (int*)d_ws;                         // ENTRIES ints
    int* cursors = entries + ENTRIES;                  // 32 ints
    float* W1Tp  = (float*)(cursors + 32);             // KK*1024 floats (4KB/k)
    float* b1p   = W1Tp + KK * 1024;                   // KK*32
    float* w2p   = b1p + KK * 32;                      // KK*32

    hipLaunchKernelGGL(prep_kernel,
                       dim3((KK * 1024 + 2 * KK * 32 + 255) / 256), dim3(256),
                       0, stream, W1, b1, W2, W1Tp, b1p, w2p, cursors);

    hipLaunchKernelGGL(bucketize_kernel, dim3(NN / 256), dim3(256), 0, stream,
                       x, entries, cursors, out);

    hipLaunchKernelGGL(mlp_kernel, dim3(KK * 32), dim3(256), 0, stream,
                       x, a, b, W1Tp, b1p, w2p, b2, entries, cursors, out);
}

// Round 7
// 52.147 us; speedup vs baseline: 10.2084x; 10.2084x over previous
//
#include <hip/hip_runtime.h>
#include <hip/hip_bf16.h>

#define NN 262144
#define DD 32
#define HH 31
#define KK 21
#define CAP 16384                 // per-bucket capacity; rows/bucket ~12483
#define ENTRIES (KK * CAP)
#define CURSTRIDE 16              // cursors padded to 64B to avoid atomic line contention

typedef __attribute__((ext_vector_type(8))) short bf16x8;
typedef __attribute__((ext_vector_type(4))) float f32x4;

static __device__ __forceinline__ short f2bf(float f) {
    __hip_bfloat16 h = __float2bfloat16(f);      // round-to-nearest-even
    return __builtin_bit_cast(short, h);
}
static __device__ __forceinline__ float bf2f(short s) {
    unsigned u = ((unsigned)(unsigned short)s) << 16;
    return __builtin_bit_cast(float, u);
}

// ---------------- Kernel 1: bucketize rows by t ----------------
__global__ __launch_bounds__(256) void bucketize_kernel(
    const float* __restrict__ x,
    int* __restrict__ entries,    // [KK][CAP]
    int* __restrict__ cursors,    // [KK*CURSTRIDE], pre-zeroed
    float* __restrict__ out)
{
    __shared__ int lcnt[KK];
    __shared__ int lbase[KK];
    __shared__ int lrank[KK];

    const int tid = threadIdx.x;
    if (tid < KK) { lcnt[tid] = 0; lrank[tid] = 0; }
    __syncthreads();

    const int n = blockIdx.x * 256 + tid;
    const float t = x[n * DD];

    // Exact same comparisons as reference: t > edges[k] && t <= edges[k+1]
    const float edges[KK + 1] = {
        0.0f, 0.1f, 0.2f, 0.3f, 0.4f, 0.5f, 0.6f, 0.7f, 0.8f, 0.9f, 1.0f,
        1.1f, 1.2f, 1.3f, 1.4f, 1.5f, 1.6f, 1.7f, 1.8f, 1.9f, 2.0f, 1000.0f
    };
    int k = -1;
    #pragma unroll
    for (int j = 0; j < KK; ++j)
        if (t > edges[j] && t <= edges[j + 1]) k = j;

    if (k >= 0) atomicAdd(&lcnt[k], 1);
    __syncthreads();
    if (tid < KK) lbase[tid] = atomicAdd(&cursors[tid * CURSTRIDE], lcnt[tid]);
    __syncthreads();
    if (k >= 0) {
        const int r = atomicAdd(&lrank[k], 1);
        const int pos = lbase[k] + r;
        if (pos < CAP) entries[k * CAP + pos] = n;
    } else {
        out[n] = 0.0f;   // rows outside every bucket
    }
}

// ---------------- Kernel 2: per-bucket MLP via bf16 MFMA ----------------
// 32 blocks/bucket, 512 rows/block, 4 waves * 8 iterations of 16-row tiles.
// Weights: persistent B-fragments in VGPRs (8 regs/tile), built once per block.
// feats hi/lo split -> error limited to W's bf16 rounding (~1.5e-2).
// Layer 2 in f32 VALU: lrelu, *w2, shfl_xor reduce over the 16 e-columns.
__global__ __launch_bounds__(256) void mlp_mfma_kernel(
    const float* __restrict__ x,
    const float* __restrict__ a,
    const float* __restrict__ b,
    const float* __restrict__ W1,
    const float* __restrict__ b1,
    const float* __restrict__ W2,
    const float* __restrict__ b2,
    const int* __restrict__ entries,
    const int* __restrict__ cursors,
    float* __restrict__ out)
{
    const int k = __builtin_amdgcn_readfirstlane((int)blockIdx.x >> 5);
    const int blk = (int)blockIdx.x & 31;
    int cnt = cursors[k * CURSTRIDE];
    if (cnt > CAP) cnt = CAP;
    const int base0 = blk * 512;
    if (base0 >= cnt) return;

    const int tid  = (int)threadIdx.x;
    const int wave = tid >> 6;
    const int lane = tid & 63;
    const int lrow = lane & 15;      // A row / C col (e)
    const int lgrp = lane >> 4;      // 0..3
    const int c0   = lgrp * 4;       // k-chunk base

    const float* __restrict__ W1k = W1 + k * (HH * HH);

    // --- B fragments (once per block). elem j: k=c0+j ; elem 4+j: k=16+c0+j.
    const int e0 = lrow;          // tile0 column, 0..15 (<HH always)
    const int e1 = 16 + lrow;     // tile1 column, 16..31 (31 invalid)
    bf16x8 B0, B1;
    #pragma unroll
    for (int j = 0; j < 4; ++j) {
        const int d1 = c0 + j;          // 0..15
        const int d2 = 16 + c0 + j;     // 16..31 (31 = pad)
        const float w00 = W1k[d1 * HH + e0];
        const float w01 = (d2 < HH) ? W1k[d2 * HH + e0] : 0.0f;
        const float w10 = (e1 < HH) ? W1k[d1 * HH + e1] : 0.0f;
        const float w11 = (e1 < HH && d2 < HH) ? W1k[d2 * HH + e1] : 0.0f;
        B0[j]     = f2bf(w00);
        B0[4 + j] = f2bf(w01);
        B1[j]     = f2bf(w10);
        B1[4 + j] = f2bf(w11);
    }

    // --- per-lane a/b constants for this lane's 8 k positions.
    float av[8], bv[8];
    #pragma unroll
    for (int j = 0; j < 4; ++j) {
        const int kk1 = c0 + j;         // < 16
        const int kk2 = 16 + c0 + j;    // may be 31 (pad)
        av[j] = a[kk1];  bv[j] = b[kk1];
        av[4 + j] = (kk2 < HH) ? a[kk2] : 0.0f;
        bv[4 + j] = (kk2 < HH) ? b[kk2] : 0.0f;
    }

    const float w2c0 = W2[k * HH + e0];
    const float w2c1 = (e1 < HH) ? W2[k * HH + e1] : 0.0f;
    const float b1c0 = b1[k * HH + e0];
    const float b1c1 = (e1 < HH) ? b1[k * HH + e1] : 0.0f;
    const float b2k  = b2[k];

    const int ebase = k * CAP;

    for (int it = wave; it < 32; it += 4) {
        const int tbase = base0 + it * 16;
        if (tbase >= cnt) break;                       // wave-uniform

        const int gi = tbase + lrow;                   // row this lane feeds
        const int n  = (gi < cnt) ? entries[ebase + gi] : 0;
        const int wi = tbase + c0 + (lane & 3);        // row this lane may write
        const int nw = (wi < cnt) ? entries[ebase + wi] : -1;

        const float* __restrict__ xr = x + n * DD;

        // feats for this lane's 8 k positions (elem index = k+1).
        float f[8];
        #pragma unroll
        for (int j = 0; j < 4; ++j)
            f[j] = fmaf(xr[c0 + 1 + j], av[j], bv[j]);
        #pragma unroll
        for (int j = 0; j < 4; ++j) {
            const int el = 17 + c0 + j;
            const float xv = (el < DD) ? xr[el] : 0.0f;
            f[4 + j] = fmaf(xv, av[4 + j], bv[4 + j]);
        }

        // hi/lo split to bf16.
        bf16x8 Ahi, Alo;
        #pragma unroll
        for (int j = 0; j < 8; ++j) {
            const short hs = f2bf(f[j]);
            Ahi[j] = hs;
            Alo[j] = f2bf(f[j] - bf2f(hs));
        }

        f32x4 acc0 = {0.0f, 0.0f, 0.0f, 0.0f};
        f32x4 acc1 = {0.0f, 0.0f, 0.0f, 0.0f};
        acc0 = __builtin_amdgcn_mfma_f32_16x16x32_bf16(Alo, B0, acc0, 0, 0, 0);
        acc0 = __builtin_amdgcn_mfma_f32_16x16x32_bf16(Ahi, B0, acc0, 0, 0, 0);
        acc1 = __builtin_amdgcn_mfma_f32_16x16x32_bf16(Alo, B1, acc1, 0, 0, 0);
        acc1 = __builtin_amdgcn_mfma_f32_16x16x32_bf16(Ahi, B1, acc1, 0, 0, 0);

        // layer 2 in f32: lrelu -> *w2 -> reduce over the 16 columns.
        float p[4];
        #pragma unroll
        for (int r = 0; r < 4; ++r) {
            const float h0 = acc0[r] + b1c0;
            const float h1 = acc1[r] + b1c1;
            const float q0 = (h0 >= 0.0f) ? h0 : 0.1f * h0;
            const float q1 = (h1 >= 0.0f) ? h1 : 0.1f * h1;
            p[r] = fmaf(q0, w2c0, q1 * w2c1);
        }
        #pragma unroll
        for (int m = 1; m <= 8; m <<= 1) {
            #pragma unroll
            for (int r = 0; r < 4; ++r) p[r] += __shfl_xor(p[r], m);
        }

        if (nw >= 0 && lrow < 4) {
            const int rs = lane & 3;
            const float v = (rs & 2) ? ((rs & 1) ? p[3] : p[2])
                                     : ((rs & 1) ? p[1] : p[0]);
            out[nw] = v + b2k;
        }
    }
}

extern "C" void kernel_launch(void* const* d_in, const int* in_sizes, int n_in,
                              void* d_out, int out_size, void* d_ws, size_t ws_size,
                              hipStream_t stream) {
    const float* x  = (const float*)d_in[0];
    const float* a  = (const float*)d_in[1];
    const float* b  = (const float*)d_in[2];
    const float* W1 = (const float*)d_in[3];
    const float* b1 = (const float*)d_in[4];
    const float* W2 = (const float*)d_in[5];
    const float* b2 = (const float*)d_in[6];
    float* out = (float*)d_out;

    int* entries = (int*)d_ws;                         // ENTRIES ints
    int* cursors = entries + ENTRIES;                  // KK*CURSTRIDE ints

    hipMemsetAsync(cursors, 0, KK * CURSTRIDE * sizeof(int), stream);

    hipLaunchKernelGGL(bucketize_kernel, dim3(NN / 256), dim3(256), 0, stream,
                       x, entries, cursors, out);

    hipLaunchKernelGGL(mlp_mfma_kernel, dim3(KK * 32), dim3(256), 0, stream,
                       x, a, b, W1, b1, W2, b2, entries, cursors, out);
}

// Round 8
// 28.464 us; speedup vs baseline: 18.7022x; 1.8320x over previous
//
#include <hip/hip_runtime.h>
#include <hip/hip_bf16.h>

#define NN 262144
#define DD 32
#define HH 31
#define KK 21
#define ROWS 256                 // rows per block == threads per block

typedef __attribute__((ext_vector_type(8))) short bf16x8;
typedef __attribute__((ext_vector_type(4))) float f32x4;

static __device__ __forceinline__ short f2bf(float f) {
    __hip_bfloat16 h = __float2bfloat16(f);      // round-to-nearest-even
    return __builtin_bit_cast(short, h);
}
static __device__ __forceinline__ float bf2f(short s) {
    unsigned u = ((unsigned)(unsigned short)s) << 16;
    return __builtin_bit_cast(float, u);
}

// One block = 256 contiguous rows. Phase 1: bucket t, LDS counting sort.
// Phase 2: prefix (rows + 16-row tiles). Phase 3: waves process tiles;
// each tile is wave-uniform in k -> bf16 MFMA with per-tile B fragments.
__global__ __launch_bounds__(256, 4) void fused_kernel(
    const float* __restrict__ x,
    const float* __restrict__ a,
    const float* __restrict__ b,
    const float* __restrict__ W1,
    const float* __restrict__ b1,
    const float* __restrict__ W2,
    const float* __restrict__ b2,
    float* __restrict__ out)
{
    __shared__ int cnt[KK];
    __shared__ int rnk[KK];
    __shared__ int sbase[KK];
    __shared__ int tstart[KK + 1];
    __shared__ unsigned short sorted[ROWS];
    __shared__ signed char karr[ROWS];

    const int tid = (int)threadIdx.x;
    const int rowbase = (int)blockIdx.x * ROWS;

    if (tid < KK) { cnt[tid] = 0; rnk[tid] = 0; }
    __syncthreads();

    // ---- Phase 1: bucket by t (exact reference comparisons) ----
    const float t = x[(size_t)(rowbase + tid) * DD];
    const float edges[KK + 1] = {
        0.0f, 0.1f, 0.2f, 0.3f, 0.4f, 0.5f, 0.6f, 0.7f, 0.8f, 0.9f, 1.0f,
        1.1f, 1.2f, 1.3f, 1.4f, 1.5f, 1.6f, 1.7f, 1.8f, 1.9f, 2.0f, 1000.0f
    };
    int kq = -1;
    #pragma unroll
    for (int j = 0; j < KK; ++j)
        if (t > edges[j] && t <= edges[j + 1]) kq = j;

    karr[tid] = (signed char)kq;
    if (kq >= 0) atomicAdd(&cnt[kq], 1);
    else out[rowbase + tid] = 0.0f;
    __syncthreads();

    // ---- Phase 2: prefix sums (rows and tiles) ----
    if (tid == 0) {
        int s = 0, ts = 0;
        #pragma unroll
        for (int j = 0; j < KK; ++j) {
            sbase[j] = s; tstart[j] = ts;
            s += cnt[j]; ts += (cnt[j] + 15) >> 4;
        }
        tstart[KK] = ts;
    }
    __syncthreads();
    {
        const int kk = karr[tid];
        if (kk >= 0) {
            const int r = atomicAdd(&rnk[kk], 1);
            sorted[sbase[kk] + r] = (unsigned short)tid;
        }
    }
    __syncthreads();

    // ---- Phase 3: MFMA over per-bucket 16-row tiles ----
    const int lane = tid & 63;
    const int wave = tid >> 6;
    const int lrow = lane & 15;      // A row / C col
    const int lgrp = lane >> 4;      // 0..3
    const int c0   = lgrp * 4;       // k-chunk base

    const int NT = tstart[KK];
    const int ts_l = tstart[(lane <= KK) ? lane : KK];  // lane-resident tile-prefix

    // per-lane a/b constants (k-independent)
    float av[8], bv[8];
    #pragma unroll
    for (int j = 0; j < 4; ++j) {
        const int k1 = c0 + j;          // < 16
        const int k2i = 16 + c0 + j;    // may be 31 (pad)
        av[j] = a[k1];  bv[j] = b[k1];
        av[4 + j] = (k2i < HH) ? a[k2i] : 0.0f;
        bv[4 + j] = (k2i < HH) ? b[k2i] : 0.0f;
    }

    const int e0 = lrow;          // tile0 output column
    const int e1 = 16 + lrow;     // tile1 output column (31 = pad)

    for (int tix = wave; tix < NT; tix += 4) {
        // k for this tile: largest j with tstart[j] <= tix (ballot+popcount)
        const unsigned long long m = __ballot(ts_l <= tix);
        const int k = __builtin_amdgcn_readfirstlane(__popcll(m) - 1);

        const int tk  = tstart[k];
        const int sb  = sbase[k];
        const int cn  = cnt[k];
        const int ti  = tix - tk;
        const int r0  = ti * 16;                  // first tile row (within bucket)

        const int rloc  = r0 + lrow;
        const bool vA   = rloc < cn;
        const int nloc  = sorted[vA ? (sb + rloc) : 0];
        const int nr    = rowbase + nloc;

        // B fragments for this k (L1/L2-hot W1)
        const float* __restrict__ W1k = W1 + k * (HH * HH);
        bf16x8 B0, B1;
        #pragma unroll
        for (int j = 0; j < 4; ++j) {
            const int d1 = c0 + j;
            const int d2 = 16 + c0 + j;
            const float w00 = W1k[d1 * HH + e0];
            const float w01 = (d2 < HH) ? W1k[d2 * HH + e0] : 0.0f;
            const float w10 = (e1 < HH) ? W1k[d1 * HH + e1] : 0.0f;
            const float w11 = (e1 < HH && d2 < HH) ? W1k[d2 * HH + e1] : 0.0f;
            B0[j]     = f2bf(w00);
            B0[4 + j] = f2bf(w01);
            B1[j]     = f2bf(w10);
            B1[4 + j] = f2bf(w11);
        }
        const float w2c0 = W2[k * HH + e0];
        const float w2c1 = (e1 < HH) ? W2[k * HH + e1] : 0.0f;
        const float b1c0 = b1[k * HH + e0];
        const float b1c1 = (e1 < HH) ? b1[k * HH + e1] : 0.0f;
        const float b2k  = b2[k];

        // A: this lane's 8 feats of row nr (L1/L2-warm from phase 1)
        const float* __restrict__ xr = x + (size_t)nr * DD;
        float f[8];
        #pragma unroll
        for (int j = 0; j < 4; ++j)
            f[j] = fmaf(xr[c0 + 1 + j], av[j], bv[j]);
        #pragma unroll
        for (int j = 0; j < 4; ++j) {
            const int el = 17 + c0 + j;
            const float xv = (el < DD) ? xr[el] : 0.0f;
            f[4 + j] = fmaf(xv, av[4 + j], bv[4 + j]);
        }

        bf16x8 Ahi, Alo;
        #pragma unroll
        for (int j = 0; j < 8; ++j) {
            const short hs = f2bf(f[j]);
            Ahi[j] = hs;
            Alo[j] = f2bf(f[j] - bf2f(hs));
        }

        f32x4 acc0 = {0.0f, 0.0f, 0.0f, 0.0f};
        f32x4 acc1 = {0.0f, 0.0f, 0.0f, 0.0f};
        acc0 = __builtin_amdgcn_mfma_f32_16x16x32_bf16(Alo, B0, acc0, 0, 0, 0);
        acc0 = __builtin_amdgcn_mfma_f32_16x16x32_bf16(Ahi, B0, acc0, 0, 0, 0);
        acc1 = __builtin_amdgcn_mfma_f32_16x16x32_bf16(Alo, B1, acc1, 0, 0, 0);
        acc1 = __builtin_amdgcn_mfma_f32_16x16x32_bf16(Ahi, B1, acc1, 0, 0, 0);

        // layer 2: lrelu -> *w2 -> reduce over 16 columns (within lane-group)
        float p[4];
        #pragma unroll
        for (int r = 0; r < 4; ++r) {
            const float h0 = acc0[r] + b1c0;
            const float h1 = acc1[r] + b1c1;
            const float q0 = (h0 >= 0.0f) ? h0 : 0.1f * h0;
            const float q1 = (h1 >= 0.0f) ? h1 : 0.1f * h1;
            p[r] = fmaf(q0, w2c0, q1 * w2c1);
        }
        #pragma unroll
        for (int s = 1; s <= 8; s <<= 1) {
            #pragma unroll
            for (int r = 0; r < 4; ++r) p[r] += __shfl_xor(p[r], s);
        }

        // write: group g lanes 0..3 write tile rows 4g+0..3
        const int rs = lane & 3;
        const int wloc = r0 + c0 + rs;
        if (lrow < 4 && wloc < cn) {
            const float v = (rs & 2) ? ((rs & 1) ? p[3] : p[2])
                                     : ((rs & 1) ? p[1] : p[0]);
            out[rowbase + sorted[sb + wloc]] = v + b2k;
        }
    }
}

extern "C" void kernel_launch(void* const* d_in, const int* in_sizes, int n_in,
                              void* d_out, int out_size, void* d_ws, size_t ws_size,
                              hipStream_t stream) {
    const float* x  = (const float*)d_in[0];
    const float* a  = (const float*)d_in[1];
    const float* b  = (const float*)d_in[2];
    const float* W1 = (const float*)d_in[3];
    const float* b1 = (const float*)d_in[4];
    const float* W2 = (const float*)d_in[5];
    const float* b2 = (const float*)d_in[6];
    float* out = (float*)d_out;

    hipLaunchKernelGGL(fused_kernel, dim3(NN / ROWS), dim3(256), 0, stream,
                       x, a, b, W1, b1, W2, b2, out);
}

// Round 9
// 21.617 us; speedup vs baseline: 24.6263x; 1.3168x over previous
//
#include <hip/hip_runtime.h>
#include <hip/hip_bf16.h>

#define NN 262144
#define DD 32
#define HH 31
#define KK 21
#define ROWS 256                 // rows per block == threads per block

typedef __attribute__((ext_vector_type(8))) short bf16x8;
typedef __attribute__((ext_vector_type(4))) float f32x4;

static __device__ __forceinline__ short f2bf(float f) {
    __hip_bfloat16 h = __float2bfloat16(f);      // round-to-nearest-even
    return __builtin_bit_cast(short, h);
}
static __device__ __forceinline__ float bf2f(short s) {
    unsigned u = ((unsigned)(unsigned short)s) << 16;
    return __builtin_bit_cast(float, u);
}

// ---------------- Prep: per-lane fragment/const tables (tiny) ----------------
// A0tab/A1tab[k][lane]: bf16 A-fragments of W1^T (row=e, k-axis=d).
// cq0b/cq0w/cq1b/cq1w[k][lane]: f32x4 {b1,w2} for e = 4*lgrp + r (+16).
__global__ __launch_bounds__(64) void prep_kernel(
    const float* __restrict__ W1, const float* __restrict__ b1,
    const float* __restrict__ W2,
    bf16x8* __restrict__ A0tab, bf16x8* __restrict__ A1tab,
    f32x4* __restrict__ cq0b, f32x4* __restrict__ cq0w,
    f32x4* __restrict__ cq1b, f32x4* __restrict__ cq1w)
{
    const int k = (int)blockIdx.x;
    const int lane = (int)threadIdx.x;
    const int lrow = lane & 15, lgrp = lane >> 4;
    const float* __restrict__ W1k = W1 + k * HH * HH;
    const int e0 = lrow, e1 = 16 + lrow;

    bf16x8 A0, A1;
    #pragma unroll
    for (int j = 0; j < 4; ++j) {
        const int d1 = 4 * lgrp + j;
        const int d2 = 16 + 4 * lgrp + j;
        A0[j]     = f2bf(W1k[d1 * HH + e0]);
        A0[4 + j] = (d2 < HH) ? f2bf(W1k[d2 * HH + e0]) : (short)0;
        A1[j]     = (e1 < HH) ? f2bf(W1k[d1 * HH + e1]) : (short)0;
        A1[4 + j] = (e1 < HH && d2 < HH) ? f2bf(W1k[d2 * HH + e1]) : (short)0;
    }
    A0tab[k * 64 + lane] = A0;
    A1tab[k * 64 + lane] = A1;

    f32x4 b0v, w0v, b1v, w1v;
    #pragma unroll
    for (int r = 0; r < 4; ++r) {
        const int e = 4 * lgrp + r, eb = 16 + e;
        b0v[r] = b1[k * HH + e];
        w0v[r] = W2[k * HH + e];
        b1v[r] = (eb < HH) ? b1[k * HH + eb] : 0.0f;
        w1v[r] = (eb < HH) ? W2[k * HH + eb] : 0.0f;
    }
    cq0b[k * 64 + lane] = b0v;
    cq0w[k * 64 + lane] = w0v;
    cq1b[k * 64 + lane] = b1v;
    cq1w[k * 64 + lane] = w1v;
}

// ---------------- Fused: sort 256 rows + MFMA tiles, all from LDS ----------
__global__ __launch_bounds__(256, 4) void fused_kernel(
    const float* __restrict__ x,
    const float* __restrict__ a,
    const float* __restrict__ b,
    const float* __restrict__ b2,
    const bf16x8* __restrict__ A0tab, const bf16x8* __restrict__ A1tab,
    const f32x4* __restrict__ cq0b, const f32x4* __restrict__ cq0w,
    const f32x4* __restrict__ cq1b, const f32x4* __restrict__ cq1w,
    float* __restrict__ out)
{
    __shared__ float fpad[ROWS * 36];      // feats, rows padded to 36 floats
    __shared__ int cnt[KK];
    __shared__ int rnk[KK];
    __shared__ int sbase[KK];
    __shared__ int tstart[KK + 1];
    __shared__ unsigned short sorted[ROWS];

    const int tid = (int)threadIdx.x;
    const int rowbase = (int)blockIdx.x * ROWS;

    if (tid < KK) { cnt[tid] = 0; rnk[tid] = 0; }
    __syncthreads();

    // ---- Phase 1: read own row (coalesced), bucket, feats -> LDS ----
    const float* __restrict__ xr = x + (size_t)(rowbase + tid) * DD;
    float4 c[8];
    #pragma unroll
    for (int i = 0; i < 8; ++i) c[i] = ((const float4*)xr)[i];
    const float t = c[0].x;

    const float edges[KK + 1] = {
        0.0f, 0.1f, 0.2f, 0.3f, 0.4f, 0.5f, 0.6f, 0.7f, 0.8f, 0.9f, 1.0f,
        1.1f, 1.2f, 1.3f, 1.4f, 1.5f, 1.6f, 1.7f, 1.8f, 1.9f, 2.0f, 1000.0f
    };
    int kq = -1;
    #pragma unroll
    for (int j = 0; j < KK; ++j)
        if (t > edges[j] && t <= edges[j + 1]) kq = j;

    // feats[e] = x[e+1]*a[e]+b[e]; f[31]=0. Written as 8 float4 slots.
    #pragma unroll
    for (int s = 0; s < 8; ++s) {
        float4 o;
        o.x = fmaf(c[s].y, a[4 * s + 0], b[4 * s + 0]);
        o.y = fmaf(c[s].z, a[4 * s + 1], b[4 * s + 1]);
        o.z = fmaf(c[s].w, a[4 * s + 2], b[4 * s + 2]);
        o.w = (s < 7) ? fmaf(c[s + 1].x, a[4 * s + 3], b[4 * s + 3]) : 0.0f;
        ((float4*)(fpad + tid * 36))[s] = o;
    }

    if (kq >= 0) atomicAdd(&cnt[kq], 1);
    else out[rowbase + tid] = 0.0f;
    __syncthreads();

    // ---- Phase 2: prefix sums (rows and 16-row tiles), scatter ----
    if (tid == 0) {
        int s = 0, ts = 0;
        #pragma unroll
        for (int j = 0; j < KK; ++j) {
            sbase[j] = s; tstart[j] = ts;
            s += cnt[j]; ts += (cnt[j] + 15) >> 4;
        }
        tstart[KK] = ts;
    }
    __syncthreads();
    if (kq >= 0) {
        const int r = atomicAdd(&rnk[kq], 1);
        sorted[sbase[kq] + r] = (unsigned short)tid;
    }
    __syncthreads();

    // ---- Phase 3: MFMA over per-bucket 16-row tiles ----
    const int lane = tid & 63;
    const int wave = tid >> 6;
    const int lrow = lane & 15;
    const int lgrp = lane >> 4;

    const int NT = tstart[KK];
    const int ts_l = tstart[(lane <= KK) ? lane : KK];

    for (int tix = wave; tix < NT; tix += 4) {
        // k = largest j with tstart[j] <= tix
        const unsigned long long m = __ballot(ts_l <= tix);
        const int k = __builtin_amdgcn_readfirstlane(__popcll(m) - 1);

        const int sb = sbase[k];
        const int cn = cnt[k];
        const int r0 = (tix - tstart[k]) * 16;
        const int rl = r0 + lrow;

        const int R = sorted[sb + ((rl < cn) ? rl : 0)];   // B col = row n

        // B fragment: feats from LDS (2x ds_read_b128), hi/lo bf16 split
        const f32x4 fv0 = ((const f32x4*)(fpad + R * 36))[lgrp];
        const f32x4 fv1 = ((const f32x4*)(fpad + R * 36))[4 + lgrp];
        bf16x8 Bhi, Blo;
        #pragma unroll
        for (int j = 0; j < 4; ++j) {
            const short h0 = f2bf(fv0[j]);
            Bhi[j] = h0; Blo[j] = f2bf(fv0[j] - bf2f(h0));
            const short h1 = f2bf(fv1[j]);
            Bhi[4 + j] = h1; Blo[4 + j] = f2bf(fv1[j] - bf2f(h1));
        }

        // A fragments + consts: coalesced dwordx4 table loads (L1/L2-hot)
        const bf16x8 A0 = A0tab[k * 64 + lane];
        const bf16x8 A1 = A1tab[k * 64 + lane];
        const f32x4 cb0 = cq0b[k * 64 + lane];
        const f32x4 cw0 = cq0w[k * 64 + lane];
        const f32x4 cb1 = cq1b[k * 64 + lane];
        const f32x4 cw1 = cq1w[k * 64 + lane];
        const float b2k = b2[k];

        f32x4 acc0 = {0.0f, 0.0f, 0.0f, 0.0f};
        f32x4 acc1 = {0.0f, 0.0f, 0.0f, 0.0f};
        acc0 = __builtin_amdgcn_mfma_f32_16x16x32_bf16(A0, Bhi, acc0, 0, 0, 0);
        acc0 = __builtin_amdgcn_mfma_f32_16x16x32_bf16(A0, Blo, acc0, 0, 0, 0);
        acc1 = __builtin_amdgcn_mfma_f32_16x16x32_bf16(A1, Bhi, acc1, 0, 0, 0);
        acc1 = __builtin_amdgcn_mfma_f32_16x16x32_bf16(A1, Blo, acc1, 0, 0, 0);

        // epilogue: lrelu -> *w2, sum 8 in-lane e's, fold 4 groups (2 xors)
        float S = 0.0f;
        #pragma unroll
        for (int r = 0; r < 4; ++r) {
            const float h0 = acc0[r] + cb0[r];
            const float q0 = (h0 >= 0.0f) ? h0 : 0.1f * h0;
            S = fmaf(q0, cw0[r], S);
            const float h1 = acc1[r] + cb1[r];
            const float q1 = (h1 >= 0.0f) ? h1 : 0.1f * h1;
            S = fmaf(q1, cw1[r], S);
        }
        S += __shfl_xor(S, 16);
        S += __shfl_xor(S, 32);

        if (lgrp == 0 && rl < cn) out[rowbase + R] = S + b2k;
    }
}

extern "C" void kernel_launch(void* const* d_in, const int* in_sizes, int n_in,
                              void* d_out, int out_size, void* d_ws, size_t ws_size,
                              hipStream_t stream) {
    const float* x  = (const float*)d_in[0];
    const float* a  = (const float*)d_in[1];
    const float* b  = (const float*)d_in[2];
    const float* W1 = (const float*)d_in[3];
    const float* b1 = (const float*)d_in[4];
    const float* W2 = (const float*)d_in[5];
    const float* b2 = (const float*)d_in[6];
    float* out = (float*)d_out;

    char* ws = (char*)d_ws;
    bf16x8* A0tab = (bf16x8*)ws;                       // 21*64*16B
    bf16x8* A1tab = A0tab + KK * 64;
    f32x4* cq0b = (f32x4*)(A1tab + KK * 64);           // 4 tables, 16B each
    f32x4* cq0w = cq0b + KK * 64;
    f32x4* cq1b = cq0w + KK * 64;
    f32x4* cq1w = cq1b + KK * 64;

    hipLaunchKernelGGL(prep_kernel, dim3(KK), dim3(64), 0, stream,
                       W1, b1, W2, A0tab, A1tab, cq0b, cq0w, cq1b, cq1w);

    hipLaunchKernelGGL(fused_kernel, dim3(NN / ROWS), dim3(256), 0, stream,
                       x, a, b, b2, A0tab, A1tab, cq0b, cq0w, cq1b, cq1w, out);
}

// Round 10
// 21.382 us; speedup vs baseline: 24.8960x; 1.0110x over previous
//
#include <hip/hip_runtime.h>
#include <hip/hip_bf16.h>

#define NN 262144
#define DD 32
#define HH 31
#define KK 21
#define ROWS 256                 // rows per block == threads per block
#define FSTRIDE 18               // u32 words per row in LDS (72 B, 8B-aligned)

typedef __attribute__((ext_vector_type(8))) short bf16x8;
typedef __attribute__((ext_vector_type(4))) float f32x4;
typedef __attribute__((ext_vector_type(2))) unsigned int u32x2;
typedef __attribute__((ext_vector_type(4))) unsigned int u32x4;

static __device__ __forceinline__ unsigned short f2bf(float f) {
    __hip_bfloat16 h = __float2bfloat16(f);      // round-to-nearest-even
    return __builtin_bit_cast(unsigned short, h);
}
static __device__ __forceinline__ unsigned pack2(float lo, float hi) {
    return (unsigned)f2bf(lo) | ((unsigned)f2bf(hi) << 16);
}

// ---------------- Prep: per-lane fragment/const tables (tiny) ----------------
// A0tab/A1tab[k][lane]: bf16 A-fragments of W1^T (row=e, k-axis=d).
// cq*[k][lane]: f32x4 {b1,w2} for e = 4*lgrp + r (+16).
__global__ __launch_bounds__(64) void prep_kernel(
    const float* __restrict__ W1, const float* __restrict__ b1,
    const float* __restrict__ W2,
    bf16x8* __restrict__ A0tab, bf16x8* __restrict__ A1tab,
    f32x4* __restrict__ cq0b, f32x4* __restrict__ cq0w,
    f32x4* __restrict__ cq1b, f32x4* __restrict__ cq1w)
{
    const int k = (int)blockIdx.x;
    const int lane = (int)threadIdx.x;
    const int lrow = lane & 15, lgrp = lane >> 4;
    const float* __restrict__ W1k = W1 + k * HH * HH;
    const int e0 = lrow, e1 = 16 + lrow;

    bf16x8 A0, A1;
    #pragma unroll
    for (int j = 0; j < 4; ++j) {
        const int d1 = 4 * lgrp + j;
        const int d2 = 16 + 4 * lgrp + j;
        A0[j]     = (short)f2bf(W1k[d1 * HH + e0]);
        A0[4 + j] = (d2 < HH) ? (short)f2bf(W1k[d2 * HH + e0]) : (short)0;
        A1[j]     = (e1 < HH) ? (short)f2bf(W1k[d1 * HH + e1]) : (short)0;
        A1[4 + j] = (e1 < HH && d2 < HH) ? (short)f2bf(W1k[d2 * HH + e1]) : (short)0;
    }
    A0tab[k * 64 + lane] = A0;
    A1tab[k * 64 + lane] = A1;

    f32x4 b0v, w0v, b1v, w1v;
    #pragma unroll
    for (int r = 0; r < 4; ++r) {
        const int e = 4 * lgrp + r, eb = 16 + e;
        b0v[r] = b1[k * HH + e];
        w0v[r] = W2[k * HH + e];
        b1v[r] = (eb < HH) ? b1[k * HH + eb] : 0.0f;
        w1v[r] = (eb < HH) ? W2[k * HH + eb] : 0.0f;
    }
    cq0b[k * 64 + lane] = b0v;
    cq0w[k * 64 + lane] = w0v;
    cq1b[k * 64 + lane] = b1v;
    cq1w[k * 64 + lane] = w1v;
}

// ---------------- Fused: sort 256 rows + MFMA tiles, feats bf16 in LDS ------
__global__ __launch_bounds__(256, 6) void fused_kernel(
    const float* __restrict__ x,
    const float* __restrict__ a,
    const float* __restrict__ b,
    const float* __restrict__ b2,
    const bf16x8* __restrict__ A0tab, const bf16x8* __restrict__ A1tab,
    const f32x4* __restrict__ cq0b, const f32x4* __restrict__ cq0w,
    const f32x4* __restrict__ cq1b, const f32x4* __restrict__ cq1w,
    float* __restrict__ out)
{
    __shared__ unsigned fbf[ROWS * FSTRIDE];   // feats as packed bf16 pairs
    __shared__ int cnt[KK];
    __shared__ int rnk[KK];
    __shared__ int sbase[KK];
    __shared__ int tstart[KK + 1];
    __shared__ unsigned short sorted[ROWS];

    const int tid = (int)threadIdx.x;
    const int rowbase = (int)blockIdx.x * ROWS;

    if (tid < KK) { cnt[tid] = 0; rnk[tid] = 0; }
    __syncthreads();

    // ---- Phase 1: coalesced row read, bucket, bf16 feats -> LDS ----
    const float* __restrict__ xr = x + (size_t)(rowbase + tid) * DD;
    float4 c[8];
    #pragma unroll
    for (int i = 0; i < 8; ++i) c[i] = ((const float4*)xr)[i];
    const float t = c[0].x;

    const float edges[KK + 1] = {
        0.0f, 0.1f, 0.2f, 0.3f, 0.4f, 0.5f, 0.6f, 0.7f, 0.8f, 0.9f, 1.0f,
        1.1f, 1.2f, 1.3f, 1.4f, 1.5f, 1.6f, 1.7f, 1.8f, 1.9f, 2.0f, 1000.0f
    };
    int kq = -1;
    #pragma unroll
    for (int j = 0; j < KK; ++j)
        if (t > edges[j] && t <= edges[j + 1]) kq = j;

    // feats[e] = x[e+1]*a[e]+b[e] (e<31), feats[31]=0; bf16 RNE, packed u32.
    unsigned* __restrict__ frow = fbf + tid * FSTRIDE;
    #pragma unroll
    for (int s = 0; s < 8; ++s) {
        const float f0 = fmaf(c[s].y, a[4 * s + 0], b[4 * s + 0]);
        const float f1 = fmaf(c[s].z, a[4 * s + 1], b[4 * s + 1]);
        const float f2 = fmaf(c[s].w, a[4 * s + 2], b[4 * s + 2]);
        const float f3 = (s < 7) ? fmaf(c[s + 1].x, a[4 * s + 3], b[4 * s + 3]) : 0.0f;
        frow[2 * s]     = pack2(f0, f1);
        frow[2 * s + 1] = pack2(f2, f3);
    }

    if (kq >= 0) atomicAdd(&cnt[kq], 1);
    else out[rowbase + tid] = 0.0f;
    __syncthreads();

    // ---- Phase 2: prefix sums (rows and 16-row tiles), scatter ----
    if (tid == 0) {
        int s = 0, ts = 0;
        #pragma unroll
        for (int j = 0; j < KK; ++j) {
            sbase[j] = s; tstart[j] = ts;
            s += cnt[j]; ts += (cnt[j] + 15) >> 4;
        }
        tstart[KK] = ts;
    }
    __syncthreads();
    if (kq >= 0) {
        const int r = atomicAdd(&rnk[kq], 1);
        sorted[sbase[kq] + r] = (unsigned short)tid;
    }
    __syncthreads();

    // ---- Phase 3: MFMA over per-bucket 16-row tiles ----
    const int lane = tid & 63;
    const int wave = tid >> 6;
    const int lrow = lane & 15;
    const int lgrp = lane >> 4;

    const int NT = tstart[KK];
    const int ts_l = tstart[(lane <= KK) ? lane : KK];

    for (int tix = wave; tix < NT; tix += 4) {
        // k = largest j with tstart[j] <= tix
        const unsigned long long m = __ballot(ts_l <= tix);
        const int k = __builtin_amdgcn_readfirstlane(__popcll(m) - 1);

        const int sb = sbase[k];
        const int cn = cnt[k];
        const int r0 = (tix - tstart[k]) * 16;
        const int rl = r0 + lrow;

        const int R = sorted[sb + ((rl < cn) ? rl : 0)];   // B col = row n

        // B fragment: 2x ds_read_b64 of pre-rounded bf16 feats
        const unsigned* __restrict__ fr = fbf + R * FSTRIDE;
        const u32x2 wlo = *(const u32x2*)(fr + 2 * lgrp);
        const u32x2 whi = *(const u32x2*)(fr + 8 + 2 * lgrp);
        u32x4 bw;
        bw[0] = wlo[0]; bw[1] = wlo[1]; bw[2] = whi[0]; bw[3] = whi[1];
        const bf16x8 B = __builtin_bit_cast(bf16x8, bw);

        // A fragments + consts: coalesced dwordx4 table loads (L2-hot)
        const bf16x8 A0 = A0tab[k * 64 + lane];
        const bf16x8 A1 = A1tab[k * 64 + lane];
        const f32x4 cb0 = cq0b[k * 64 + lane];
        const f32x4 cw0 = cq0w[k * 64 + lane];
        const f32x4 cb1 = cq1b[k * 64 + lane];
        const f32x4 cw1 = cq1w[k * 64 + lane];
        const float b2k = b2[k];

        f32x4 acc0 = {0.0f, 0.0f, 0.0f, 0.0f};
        f32x4 acc1 = {0.0f, 0.0f, 0.0f, 0.0f};
        acc0 = __builtin_amdgcn_mfma_f32_16x16x32_bf16(A0, B, acc0, 0, 0, 0);
        acc1 = __builtin_amdgcn_mfma_f32_16x16x32_bf16(A1, B, acc1, 0, 0, 0);

        // epilogue: lrelu -> *w2, sum 8 in-lane e's, fold 4 groups (2 xors)
        float S = 0.0f;
        #pragma unroll
        for (int r = 0; r < 4; ++r) {
            const float h0 = acc0[r] + cb0[r];
            const float q0 = (h0 >= 0.0f) ? h0 : 0.1f * h0;
            S = fmaf(q0, cw0[r], S);
            const float h1 = acc1[r] + cb1[r];
            const float q1 = (h1 >= 0.0f) ? h1 : 0.1f * h1;
            S = fmaf(q1, cw1[r], S);
        }
        S += __shfl_xor(S, 16);
        S += __shfl_xor(S, 32);

        if (lgrp == 0 && rl < cn) out[rowbase + R] = S + b2k;
    }
}

extern "C" void kernel_launch(void* const* d_in, const int* in_sizes, int n_in,
                              void* d_out, int out_size, void* d_ws, size_t ws_size,
                              hipStream_t stream) {
    const float* x  = (const float*)d_in[0];
    const float* a  = (const float*)d_in[1];
    const float* b  = (const float*)d_in[2];
    const float* W1 = (const float*)d_in[3];
    const float* b1 = (const float*)d_in[4];
    const float* W2 = (const float*)d_in[5];
    const float* b2 = (const float*)d_in[6];
    float* out = (float*)d_out;

    char* ws = (char*)d_ws;
    bf16x8* A0tab = (bf16x8*)ws;                       // 21*64*16B
    bf16x8* A1tab = A0tab + KK * 64;
    f32x4* cq0b = (f32x4*)(A1tab + KK * 64);           // 4 tables, 16B each
    f32x4* cq0w = cq0b + KK * 64;
    f32x4* cq1b = cq0w + KK * 64;
    f32x4* cq1w = cq1b + KK * 64;

    hipLaunchKernelGGL(prep_kernel, dim3(KK), dim3(64), 0, stream,
                       W1, b1, W2, A0tab, A1tab, cq0b, cq0w, cq1b, cq1w);

    hipLaunchKernelGGL(fused_kernel, dim3(NN / ROWS), dim3(256), 0, stream,
                       x, a, b, b2, A0tab, A1tab, cq0b, cq0w, cq1b, cq1w, out);
}